// Round 7
// baseline (681.648 us; speedup 1.0000x reference)
//
#include <hip/hip_runtime.h>
#include <math.h>

#define N_HIST 200000
#define TOPIC 128
#define HID 128
#define KSEL 50
#define NBINS 1024           // 10-bit order-key bins (sign+8exp+1mant)
#define NHISTBLK 64
#define NCOLLECT 128
#define NPOOL 32
#define POOL_CAP 256
#define NEG_INF (-3.402823466e38f)
// log(float32(1.0 - 1e-7)) = log(0.99999988079071045)
#define LOG_DECAY (-1.1920930e-07f)

// ws layout (4-byte words): ctrl+tot zeroed by alpha_kernel's first blocks.
enum { WS_CTRL  = 0,                       // 64: [0]=hist ticket [2]=B [8..39] pool counts
       WS_TOT   = 64,                      // 1024
       WS_ZEND  = WS_TOT + NBINS,          // 1088 = zero region end
       WS_ALPHA = WS_ZEND,                 // 200000
       WS_POOLV = WS_ALPHA + N_HIST,       // 8192
       WS_POOLI = WS_POOLV + NPOOL * POOL_CAP,  // 8192
       WS_GI    = WS_POOLI + NPOOL * POOL_CAP,  // 384
       WS_GH    = WS_GI + 3 * HID };            // 384

__device__ __forceinline__ unsigned keyOf(float f) {
    unsigned u = __float_as_uint(f);
    return (u & 0x80000000u) ? ~u : (u | 0x80000000u);
}

// Kernel 1: alpha[i] = dot(vs[i], v); first blocks also zero ctrl+tot.
__global__ __launch_bounds__(256) void alpha_kernel(
        const float* __restrict__ vs, const float* __restrict__ v,
        float* __restrict__ alpha, unsigned* __restrict__ wsbase) {
    const int zi = blockIdx.x * 256 + threadIdx.x;
    if (zi < WS_ZEND) wsbase[zi] = 0;
    const int lane = threadIdx.x & 63;
    const int wave = (blockIdx.x * blockDim.x + threadIdx.x) >> 6;
    const int half = lane >> 5;
    const int c = lane & 31;
    const int base = wave * 16 + half * 8;
    const float4 vv = ((const float4*)v)[c];
    float4 a[8];
    #pragma unroll
    for (int r = 0; r < 8; ++r)
        a[r] = ((const float4*)vs)[(size_t)(base + r) * 32 + c];
    float s[8];
    #pragma unroll
    for (int r = 0; r < 8; ++r)
        s[r] = a[r].x * vv.x + a[r].y * vv.y + a[r].z * vv.z + a[r].w * vv.w;
    #pragma unroll
    for (int off = 16; off; off >>= 1) {
        #pragma unroll
        for (int r = 0; r < 8; ++r) s[r] += __shfl_xor(s[r], off);
    }
    if (c == 0) {
        float4* dst = (float4*)(alpha + base);
        dst[0] = make_float4(s[0], s[1], s[2], s[3]);
        dst[1] = make_float4(s[4], s[5], s[6], s[7]);
    }
}

// Kernel 2: 10-bit histogram (float4 reads, packed 2x16-bit LDS bins, global
// merge of nonzero bins) + threshold scan in the LAST block, wave-parallel.
__global__ __launch_bounds__(256) void hist_kernel(
        const float* __restrict__ alpha, unsigned* __restrict__ tot,
        unsigned* __restrict__ ctrl) {
    __shared__ unsigned h[NBINS / 2];
    __shared__ unsigned lt[NBINS];
    __shared__ int sLast;
    const int t = threadIdx.x;
    #pragma unroll
    for (int i = t; i < NBINS / 2; i += 256) h[i] = 0;
    __syncthreads();
    const float4* a4 = (const float4*)alpha;
    for (int i4 = blockIdx.x * 256 + t; i4 < N_HIST / 4; i4 += NHISTBLK * 256) {
        float4 av = a4[i4];
        #pragma unroll
        for (int r = 0; r < 4; ++r) {
            unsigned b = keyOf((&av.x)[r]) >> 22;
            atomicAdd(&h[b >> 1], (b & 1u) ? 65536u : 1u);
        }
    }
    __syncthreads();
    #pragma unroll
    for (int wd = t; wd < NBINS / 2; wd += 256) {
        unsigned pk = h[wd];
        unsigned lo = pk & 0xFFFFu, hi = pk >> 16;
        if (lo) atomicAdd(&tot[2 * wd], lo);
        if (hi) atomicAdd(&tot[2 * wd + 1], hi);
    }
    __syncthreads();
    if (t == 0) {
        __threadfence();
        sLast = (atomicAdd(&ctrl[0], 1u) == NHISTBLK - 1) ? 1 : 0;
    }
    __syncthreads();
    if (sLast) {
        __threadfence();
        #pragma unroll
        for (int i = t; i < NBINS; i += 256) lt[i] = tot[i];
        __syncthreads();
        if (t < 64) {
            const int l = t;
            const int g = 63 - l;                 // lane l covers group g, descending
            unsigned s = 0;
            #pragma unroll
            for (int j = 0; j < 16; ++j) s += lt[g * 16 + j];
            unsigned pre = s;                     // inclusive prefix over descending groups
            #pragma unroll
            for (int d = 1; d <= 32; d <<= 1) {
                unsigned y = __shfl_up(pre, d);
                if (l >= d) pre += y;
            }
            unsigned long long bal = __ballot(pre >= KSEL);
            const int lstar = __ffsll(bal) - 1;
            const unsigned cumAbove = __shfl(pre - s, lstar);
            const int gstar = 63 - lstar;
            unsigned h2 = (l < 16) ? lt[gstar * 16 + (15 - l)] : 0u;
            unsigned pre2 = h2;
            #pragma unroll
            for (int d = 1; d <= 8; d <<= 1) {
                unsigned y = __shfl_up(pre2, d);
                if (l >= d) pre2 += y;
            }
            unsigned long long bal2 = __ballot((l < 16) && (cumAbove + pre2 >= KSEL));
            const int l2 = __ffsll(bal2) - 1;
            if (l == 0) ctrl[2] = (unsigned)(gstar * 16 + (15 - l2));
        }
    }
}

// Kernel 3 (fused): blocks 0..127 collect candidates (key10 >= B, float4
// reads, wave-aggregated pool appends); blocks 128..223 do the GRU matvecs.
__global__ __launch_bounds__(256) void mid_kernel(
        const float* __restrict__ alpha, unsigned* __restrict__ ctrl,
        float* __restrict__ poolV, unsigned* __restrict__ poolI,
        const float* __restrict__ v, const float* __restrict__ s_in,
        const float* __restrict__ hs,
        const float* __restrict__ W_ih, const float* __restrict__ b_ih,
        const float* __restrict__ W_hh, const float* __restrict__ b_hh,
        float* __restrict__ gi, float* __restrict__ gh) {
    const int t = threadIdx.x;
    if (blockIdx.x < NCOLLECT) {
        const unsigned B = ctrl[2];
        const int lane = t & 63;
        const int pool = blockIdx.x & (NPOOL - 1);
        const float4* a4 = (const float4*)alpha;
        for (int i4 = blockIdx.x * 256 + t; i4 < N_HIST / 4; i4 += NCOLLECT * 256) {
            float4 av = a4[i4];
            #pragma unroll
            for (int r = 0; r < 4; ++r) {
                float a = (&av.x)[r];
                bool cand = (keyOf(a) >> 22) >= B;
                unsigned long long m = __ballot(cand);
                if (m) {
                    int leader = __ffsll(m) - 1;
                    unsigned base = 0;
                    if (lane == leader) base = atomicAdd(&ctrl[8 + pool], (unsigned)__popcll(m));
                    base = __shfl(base, leader);
                    if (cand) {
                        unsigned pos = base + (unsigned)__popcll(m & ((1ull << lane) - 1ull));
                        if (pos < POOL_CAP) {
                            poolV[pool * POOL_CAP + pos] = a;
                            poolI[pool * POOL_CAP + pos] = (unsigned)(4 * i4 + r);
                        }
                    }
                }
            }
        }
    } else {
        // GRU matvec: one wave per output row o.
        const int o = ((int)blockIdx.x - NCOLLECT) * 4 + (t >> 6);
        const int l = t & 63;
        const float* wi = W_ih + (size_t)o * (TOPIC + 1);
        float pi = wi[l] * v[l] + wi[64 + l] * v[64 + l];
        if (l == 0) pi += wi[TOPIC] * s_in[0];
        const float2 wh = ((const float2*)(W_hh + (size_t)o * HID))[l];
        const float2 hh = ((const float2*)(hs + (size_t)(N_HIST - 1) * HID))[l];
        float ph = wh.x * hh.x + wh.y * hh.y;
        #pragma unroll
        for (int off = 32; off; off >>= 1) {
            pi += __shfl_xor(pi, off);
            ph += __shfl_xor(ph, off);
        }
        if (l == 0) {
            gi[o] = pi + b_ih[o];
            gh[o] = ph + b_hh[o];
        }
    }
}

// Kernel 4: fully wave-parallel finale. Prefix-scan via shfl_up, ballot-rank
// top-50, shuffle-reduce softmax, unrolled attn gather, score + GRU gates.
__global__ __launch_bounds__(512) void final_kernel(
        const float* __restrict__ v, const float* __restrict__ t_in,
        const float* __restrict__ hs, const float* __restrict__ ts,
        const float* __restrict__ W_score, const float* __restrict__ b_score,
        const unsigned* __restrict__ ctrl,
        const float* __restrict__ poolV, const unsigned* __restrict__ poolI,
        const float* __restrict__ giW, const float* __restrict__ ghW,
        float* __restrict__ out) {
    __shared__ float candV[NPOOL * POOL_CAP];
    __shared__ unsigned candI[NPOOL * POOL_CAP];
    __shared__ int off[NPOOL + 1];
    __shared__ float selV[KSEL];
    __shared__ unsigned selI[KSEL];
    __shared__ float w[KSEL];
    __shared__ float xv[TOPIC];
    __shared__ float h0[HID];
    __shared__ float attnP[8][130];
    __shared__ float red[HID];

    const int t = threadIdx.x;
    const int wv = t >> 6, l = t & 63;

    // Phase 0: wave0 prefix-scans pool counts; other waves stage xv/h0.
    if (wv == 0) {
        unsigned pcv = (l < NPOOL) ? min(ctrl[8 + l], (unsigned)POOL_CAP) : 0u;
        int x = (int)pcv;
        #pragma unroll
        for (int d = 1; d < 32; d <<= 1) {
            int y = __shfl_up(x, d);
            if (l >= d) x += y;
        }
        if (l < NPOOL) off[l] = x - (int)pcv;
        if (l == NPOOL - 1) off[NPOOL] = x;
    } else if (t >= 64 && t < 192) {
        xv[t - 64] = v[t - 64];
    } else if (t >= 192 && t < 320) {
        h0[t - 192] = hs[(size_t)(N_HIST - 1) * HID + (t - 192)];
    }
    __syncthreads();

    const int Scand = off[NPOOL];
    const int S = Scand < KSEL ? Scand : KSEL;

    // Phase 1: compact pools -> cand arrays, 16 threads per pool.
    {
        const int p = t >> 4, i0 = t & 15;
        const int base = off[p], cnt = off[p + 1] - base;
        for (int i = i0; i < cnt; i += 16) {
            candV[base + i] = poolV[p * POOL_CAP + i];
            candI[base + i] = poolI[p * POOL_CAP + i];
        }
    }
    __syncthreads();

    // Phase 2: ballot-rank selection; wave wv handles candidates wv, wv+8, ...
    for (int c = wv; c < Scand; c += 8) {
        const float mv = candV[c];
        const unsigned mi = candI[c];
        int cnt = 0;
        for (int j0 = 0; j0 < Scand; j0 += 64) {
            const int j = j0 + l;
            bool gt = false;
            if (j < Scand) {
                const float vj = candV[j];
                const unsigned ij = candI[j];
                gt = (vj > mv) || ((vj == mv) && (ij < mi));
            }
            cnt += (int)__popcll(__ballot(gt));
        }
        if (l == 0 && cnt < KSEL) { selV[cnt] = mv; selI[cnt] = mi; }
    }
    __syncthreads();

    // Phase 3: decay + softmax on wave 0, shuffle reductions.
    if (wv == 0) {
        const float tt = t_in[0];
        float dv = NEG_INF;
        if (l < S) dv = selV[l] * expf((tt - ts[selI[l]]) * LOG_DECAY);
        float m = dv;
        #pragma unroll
        for (int o = 32; o; o >>= 1) m = fmaxf(m, __shfl_xor(m, o));
        float e = (l < S) ? expf(dv - m) : 0.f;
        float sum = e;
        #pragma unroll
        for (int o = 32; o; o >>= 1) sum += __shfl_xor(sum, o);
        if (l < S) w[l] = e / sum;
    }
    __syncthreads();

    // Phase 4: attn partials; fixed 7-trip unroll -> independent gathers.
    {
        float2 acc = make_float2(0.f, 0.f);
        #pragma unroll
        for (int j = 0; j < 7; ++j) {
            const int k = wv + 8 * j;
            const bool ok = (k < S);
            const float wk = ok ? w[k] : 0.f;
            const unsigned ridx = ok ? selI[k] : 0u;
            const float2 hv = ((const float2*)(hs + (size_t)ridx * HID))[l];
            acc.x += wk * hv.x; acc.y += wk * hv.y;
        }
        attnP[wv][2 * l]     = acc.x;
        attnP[wv][2 * l + 1] = acc.y;
    }
    __syncthreads();

    // Phase 5: score partial + GRU gates.
    if (t < HID) {
        float ah = 0.f;
        #pragma unroll
        for (int g = 0; g < 8; ++g) ah += attnP[g][t];
        red[t] = xv[t] * W_score[t] + ah * W_score[HID + t];
        const float r = 1.f / (1.f + expf(-(giW[t] + ghW[t])));
        const float z = 1.f / (1.f + expf(-(giW[HID + t] + ghW[HID + t])));
        const float n = tanhf(giW[2 * HID + t] + r * ghW[2 * HID + t]);
        out[1 + t] = (1.f - z) * n + z * h0[t];
    }
    __syncthreads();

    if (t < 64) {
        float sv = red[t] + red[64 + t];
        #pragma unroll
        for (int o = 32; o; o >>= 1) sv += __shfl_xor(sv, o);
        if (t == 0) out[0] = sv + b_score[0];
    }
}

extern "C" void kernel_launch(void* const* d_in, const int* in_sizes, int n_in,
                              void* d_out, int out_size, void* d_ws, size_t ws_size,
                              hipStream_t stream) {
    const float* v       = (const float*)d_in[0];
    const float* s_in    = (const float*)d_in[1];
    const float* t_in    = (const float*)d_in[2];
    const float* vs      = (const float*)d_in[3];
    const float* hs      = (const float*)d_in[4];
    const float* ts      = (const float*)d_in[5];
    const float* W_ih    = (const float*)d_in[6];
    const float* b_ih    = (const float*)d_in[7];
    const float* W_hh    = (const float*)d_in[8];
    const float* b_hh    = (const float*)d_in[9];
    const float* W_score = (const float*)d_in[10];
    const float* b_score = (const float*)d_in[11];
    float* out = (float*)d_out;

    unsigned* ws   = (unsigned*)d_ws;
    unsigned* ctrl = ws + WS_CTRL;
    unsigned* tot  = ws + WS_TOT;
    float*    alpha = (float*)(ws + WS_ALPHA);
    float*    poolV = (float*)(ws + WS_POOLV);
    unsigned* poolI = ws + WS_POOLI;
    float*    giW   = (float*)(ws + WS_GI);
    float*    ghW   = (float*)(ws + WS_GH);

    alpha_kernel<<<3125, 256, 0, stream>>>(vs, v, alpha, ws);
    hist_kernel<<<NHISTBLK, 256, 0, stream>>>(alpha, tot, ctrl);
    mid_kernel<<<NCOLLECT + 96, 256, 0, stream>>>(alpha, ctrl, poolV, poolI,
                                                  v, s_in, hs, W_ih, b_ih, W_hh, b_hh,
                                                  giW, ghW);
    final_kernel<<<1, 512, 0, stream>>>(v, t_in, hs, ts, W_score, b_score,
                                        ctrl, poolV, poolI, giW, ghW, out);
}

// Round 8
// 67.361 us; speedup vs baseline: 10.1193x; 10.1193x over previous
//
#include <hip/hip_runtime.h>
#include <math.h>

#define N_HIST 200000
#define TOPIC 128
#define HID 128
#define KSEL 50
#define NBINS 1024           // 10-bit order-key bins (sign+8exp+1mant)
#define NHISTBLK 64
#define NCOLLECT 128
#define NPOOL 32
#define POOL_CAP 512
#define NEG_INF (-3.402823466e38f)
// log(float32(1.0 - 1e-7)) = log(0.99999988079071045)
#define LOG_DECAY (-1.1920930e-07f)

// ws layout (4-byte words): ctrl+tot zeroed by alpha_kernel's first blocks.
enum { WS_CTRL  = 0,                       // 64: [0]=hist ticket [2]=B [8..39] pool counts
       WS_TOT   = 64,                      // 1024
       WS_ZEND  = WS_TOT + NBINS,          // 1088 = zero region end
       WS_ALPHA = WS_ZEND,                 // 200000
       WS_POOLV = WS_ALPHA + N_HIST,       // 16384
       WS_POOLI = WS_POOLV + NPOOL * POOL_CAP,  // 16384
       WS_GI    = WS_POOLI + NPOOL * POOL_CAP,  // 384
       WS_GH    = WS_GI + 3 * HID };            // 384

__device__ __forceinline__ unsigned keyOf(float f) {
    unsigned u = __float_as_uint(f);
    return (u & 0x80000000u) ? ~u : (u | 0x80000000u);
}

// Kernel 1: alpha[i] = dot(vs[i], v); first blocks also zero ctrl+tot.
__global__ __launch_bounds__(256) void alpha_kernel(
        const float* __restrict__ vs, const float* __restrict__ v,
        float* __restrict__ alpha, unsigned* __restrict__ wsbase) {
    const int zi = blockIdx.x * 256 + threadIdx.x;
    if (zi < WS_ZEND) wsbase[zi] = 0;
    const int lane = threadIdx.x & 63;
    const int wave = (blockIdx.x * blockDim.x + threadIdx.x) >> 6;
    const int half = lane >> 5;
    const int c = lane & 31;
    const int base = wave * 16 + half * 8;
    const float4 vv = ((const float4*)v)[c];
    float4 a[8];
    #pragma unroll
    for (int r = 0; r < 8; ++r)
        a[r] = ((const float4*)vs)[(size_t)(base + r) * 32 + c];
    float s[8];
    #pragma unroll
    for (int r = 0; r < 8; ++r)
        s[r] = a[r].x * vv.x + a[r].y * vv.y + a[r].z * vv.z + a[r].w * vv.w;
    #pragma unroll
    for (int off = 16; off; off >>= 1) {
        #pragma unroll
        for (int r = 0; r < 8; ++r) s[r] += __shfl_xor(s[r], off);
    }
    if (c == 0) {
        float4* dst = (float4*)(alpha + base);
        dst[0] = make_float4(s[0], s[1], s[2], s[3]);
        dst[1] = make_float4(s[4], s[5], s[6], s[7]);
    }
}

// Kernel 2: 10-bit histogram (float4 reads, packed 2x16-bit LDS bins, global
// merge of nonzero bins) + threshold scan in the LAST block, wave-parallel.
__global__ __launch_bounds__(256) void hist_kernel(
        const float* __restrict__ alpha, unsigned* __restrict__ tot,
        unsigned* __restrict__ ctrl) {
    __shared__ unsigned h[NBINS / 2];
    __shared__ unsigned lt[NBINS];
    __shared__ int sLast;
    const int t = threadIdx.x;
    #pragma unroll
    for (int i = t; i < NBINS / 2; i += 256) h[i] = 0;
    __syncthreads();
    const float4* a4 = (const float4*)alpha;
    for (int i4 = blockIdx.x * 256 + t; i4 < N_HIST / 4; i4 += NHISTBLK * 256) {
        float4 av = a4[i4];
        #pragma unroll
        for (int r = 0; r < 4; ++r) {
            unsigned b = keyOf((&av.x)[r]) >> 22;
            atomicAdd(&h[b >> 1], (b & 1u) ? 65536u : 1u);
        }
    }
    __syncthreads();
    #pragma unroll
    for (int wd = t; wd < NBINS / 2; wd += 256) {
        unsigned pk = h[wd];
        unsigned lo = pk & 0xFFFFu, hi = pk >> 16;
        if (lo) atomicAdd(&tot[2 * wd], lo);
        if (hi) atomicAdd(&tot[2 * wd + 1], hi);
    }
    __syncthreads();
    if (t == 0) {
        __threadfence();
        sLast = (atomicAdd(&ctrl[0], 1u) == NHISTBLK - 1) ? 1 : 0;
    }
    __syncthreads();
    if (sLast) {
        __threadfence();
        #pragma unroll
        for (int i = t; i < NBINS; i += 256) lt[i] = tot[i];
        __syncthreads();
        if (t < 64) {
            const int l = t;
            const int g = 63 - l;                 // lane l covers group g, descending
            unsigned s = 0;
            #pragma unroll
            for (int j = 0; j < 16; ++j) s += lt[g * 16 + j];
            unsigned pre = s;                     // inclusive prefix over descending groups
            #pragma unroll
            for (int d = 1; d <= 32; d <<= 1) {
                unsigned y = __shfl_up(pre, d);
                if (l >= d) pre += y;
            }
            unsigned long long bal = __ballot(pre >= KSEL);
            const int lstar = __ffsll(bal) - 1;
            const unsigned cumAbove = __shfl(pre - s, lstar);
            const int gstar = 63 - lstar;
            unsigned h2 = (l < 16) ? lt[gstar * 16 + (15 - l)] : 0u;
            unsigned pre2 = h2;
            #pragma unroll
            for (int d = 1; d <= 8; d <<= 1) {
                unsigned y = __shfl_up(pre2, d);
                if (l >= d) pre2 += y;
            }
            unsigned long long bal2 = __ballot((l < 16) && (cumAbove + pre2 >= KSEL));
            const int l2 = __ffsll(bal2) - 1;
            if (l == 0) ctrl[2] = (unsigned)(gstar * 16 + (15 - l2));
        }
    }
}

// Kernel 3 (fused): blocks 0..127 collect candidates (key10 >= B, float4
// reads, wave-aggregated pool appends); blocks 128..223 do the GRU matvecs.
__global__ __launch_bounds__(256) void mid_kernel(
        const float* __restrict__ alpha, unsigned* __restrict__ ctrl,
        float* __restrict__ poolV, unsigned* __restrict__ poolI,
        const float* __restrict__ v, const float* __restrict__ s_in,
        const float* __restrict__ hs,
        const float* __restrict__ W_ih, const float* __restrict__ b_ih,
        const float* __restrict__ W_hh, const float* __restrict__ b_hh,
        float* __restrict__ gi, float* __restrict__ gh) {
    const int t = threadIdx.x;
    if (blockIdx.x < NCOLLECT) {
        const unsigned B = ctrl[2];
        const int lane = t & 63;
        const int pool = blockIdx.x & (NPOOL - 1);
        const float4* a4 = (const float4*)alpha;
        for (int i4 = blockIdx.x * 256 + t; i4 < N_HIST / 4; i4 += NCOLLECT * 256) {
            float4 av = a4[i4];
            #pragma unroll
            for (int r = 0; r < 4; ++r) {
                float a = (&av.x)[r];
                bool cand = (keyOf(a) >> 22) >= B;
                unsigned long long m = __ballot(cand);
                if (m) {
                    int leader = __ffsll(m) - 1;
                    unsigned base = 0;
                    if (lane == leader) base = atomicAdd(&ctrl[8 + pool], (unsigned)__popcll(m));
                    base = __shfl(base, leader);
                    if (cand) {
                        unsigned pos = base + (unsigned)__popcll(m & ((1ull << lane) - 1ull));
                        if (pos < POOL_CAP) {
                            poolV[pool * POOL_CAP + pos] = a;
                            poolI[pool * POOL_CAP + pos] = (unsigned)(4 * i4 + r);
                        }
                    }
                }
            }
        }
    } else {
        // GRU matvec: one wave per output row o.
        const int o = ((int)blockIdx.x - NCOLLECT) * 4 + (t >> 6);
        const int l = t & 63;
        const float* wi = W_ih + (size_t)o * (TOPIC + 1);
        float pi = wi[l] * v[l] + wi[64 + l] * v[64 + l];
        if (l == 0) pi += wi[TOPIC] * s_in[0];
        const float2 wh = ((const float2*)(W_hh + (size_t)o * HID))[l];
        const float2 hh = ((const float2*)(hs + (size_t)(N_HIST - 1) * HID))[l];
        float ph = wh.x * hh.x + wh.y * hh.y;
        #pragma unroll
        for (int off = 32; off; off >>= 1) {
            pi += __shfl_xor(pi, off);
            ph += __shfl_xor(ph, off);
        }
        if (l == 0) {
            gi[o] = pi + b_ih[o];
            gh[o] = ph + b_hh[o];
        }
    }
}

// Kernel 4: second-level radix select (11 more key bits) -> top-50 set in
// O(candidates/512) work, then decay+softmax+attn+score+GRU gates.
__global__ __launch_bounds__(512) void final_kernel(
        const float* __restrict__ v, const float* __restrict__ t_in,
        const float* __restrict__ hs, const float* __restrict__ ts,
        const float* __restrict__ W_score, const float* __restrict__ b_score,
        const unsigned* __restrict__ ctrl,
        const float* __restrict__ poolV, const unsigned* __restrict__ poolI,
        const float* __restrict__ giW, const float* __restrict__ ghW,
        float* __restrict__ out) {
    __shared__ unsigned hist2[2048];
    __shared__ unsigned pcnt[NPOOL];
    __shared__ unsigned cHi, selCnt, eqCnt, sB2;
    __shared__ float selV[64];
    __shared__ unsigned selI[64];
    __shared__ float eqV[256];
    __shared__ unsigned eqI[256];
    __shared__ float w[64];
    __shared__ float xv[TOPIC];
    __shared__ float h0[HID];
    __shared__ float attnP[8][130];
    __shared__ float red[HID];

    const int t = threadIdx.x;
    const int wv = t >> 6, l = t & 63;
    const unsigned B = ctrl[2];

    for (int i = t; i < 2048; i += 512) hist2[i] = 0;
    if (t < NPOOL) pcnt[t] = min(ctrl[8 + t], (unsigned)POOL_CAP);
    if (t == 0) { cHi = 0; selCnt = 0; eqCnt = 0; }
    if (t >= 128 && t < 256) xv[t - 128] = v[t - 128];
    if (t >= 256 && t < 384) h0[t - 256] = hs[(size_t)(N_HIST - 1) * HID + (t - 256)];
    __syncthreads();

    // Pass A: sub-bin histogram of ==B candidates; count >B ones.
    for (int j = t; j < NPOOL * POOL_CAP; j += 512) {
        const int p = j >> 9;               // POOL_CAP = 512
        const int idx = j & (POOL_CAP - 1);
        if (idx < (int)pcnt[p]) {
            unsigned k = keyOf(poolV[j]);
            if ((k >> 22) > B) atomicAdd(&cHi, 1u);
            else atomicAdd(&hist2[(k >> 11) & 2047], 1u);
        }
    }
    __syncthreads();

    // Wave-0 scan: find sub-bin B2 (descending two-level: 64 groups x 32).
    if (wv == 0) {
        const unsigned chi = cHi;
        const int g = 63 - l;
        unsigned s = 0;
        #pragma unroll
        for (int j = 0; j < 32; ++j) s += hist2[g * 32 + j];
        unsigned pre = s;
        #pragma unroll
        for (int d = 1; d <= 32; d <<= 1) {
            unsigned y = __shfl_up(pre, d);
            if (l >= d) pre += y;
        }
        unsigned long long bal = __ballot(chi + pre >= KSEL);
        const int lstar = __ffsll(bal) - 1;
        const unsigned cumAbove = chi + __shfl(pre - s, lstar);
        const int gstar = 63 - lstar;
        unsigned h2 = (l < 32) ? hist2[gstar * 32 + (31 - l)] : 0u;
        unsigned pre2 = h2;
        #pragma unroll
        for (int d = 1; d <= 16; d <<= 1) {
            unsigned y = __shfl_up(pre2, d);
            if (l >= d) pre2 += y;
        }
        unsigned long long bal2 = __ballot((l < 32) && (cumAbove + pre2 >= KSEL));
        const int l2 = __ffsll(bal2) - 1;
        if (l == 0) sB2 = (unsigned)(gstar * 32 + (31 - l2));
    }
    __syncthreads();
    const unsigned B2 = sB2;

    // Pass B: append strictly-above set (unordered) + 21-bit-tie pool.
    for (int j = t; j < NPOOL * POOL_CAP; j += 512) {
        const int p = j >> 9;
        const int idx = j & (POOL_CAP - 1);
        if (idx < (int)pcnt[p]) {
            float a = poolV[j];
            unsigned k = keyOf(a);
            unsigned top = k >> 22, sub = (k >> 11) & 2047;
            bool hi = (top > B) || (top == B && sub > B2);
            bool eq = (top == B) && (sub == B2);
            if (hi) {
                unsigned pos = atomicAdd(&selCnt, 1u);
                if (pos < 64u) { selV[pos] = a; selI[pos] = poolI[j]; }
            } else if (eq) {
                unsigned pos = atomicAdd(&eqCnt, 1u);
                if (pos < 256u) { eqV[pos] = a; eqI[pos] = poolI[j]; }
            }
        }
    }
    __syncthreads();

    const int Scnt = min((int)selCnt, 64);      // guaranteed < KSEL by B2
    const int eqN = min((int)eqCnt, 256);
    int need = KSEL - Scnt;
    if (need < 0) need = 0;
    if (need > eqN) need = eqN;
    const int S = Scnt + need;

    // Rank tie pool exactly (value desc, index asc); eqN is tiny.
    if (wv == 0 && need > 0) {
        for (int c = l; c < eqN; c += 64) {
            const float mv = eqV[c];
            const unsigned mi = eqI[c];
            int r = 0;
            for (int j = 0; j < eqN; ++j) {
                const float vj = eqV[j];
                const unsigned ij = eqI[j];
                r += (int)((vj > mv) | ((vj == mv) & (ij < mi)));
            }
            if (r < need) { selV[Scnt + r] = mv; selI[Scnt + r] = mi; }
        }
    }
    __syncthreads();

    // Decay + softmax on wave 0 (order-invariant downstream).
    if (wv == 0) {
        const float tt = t_in[0];
        float dv = NEG_INF;
        if (l < S) dv = selV[l] * expf((tt - ts[selI[l]]) * LOG_DECAY);
        float m = dv;
        #pragma unroll
        for (int o = 32; o; o >>= 1) m = fmaxf(m, __shfl_xor(m, o));
        float e = (l < S) ? expf(dv - m) : 0.f;
        float sum = e;
        #pragma unroll
        for (int o = 32; o; o >>= 1) sum += __shfl_xor(sum, o);
        if (l < S) w[l] = e / sum;
    }
    __syncthreads();

    // Attn partials; fixed 7-trip unroll -> independent gathers.
    {
        float2 acc = make_float2(0.f, 0.f);
        #pragma unroll
        for (int j = 0; j < 7; ++j) {
            const int k = wv + 8 * j;
            const bool ok = (k < S);
            const float wk = ok ? w[k] : 0.f;
            const unsigned ridx = ok ? selI[k] : 0u;
            const float2 hv = ((const float2*)(hs + (size_t)ridx * HID))[l];
            acc.x += wk * hv.x; acc.y += wk * hv.y;
        }
        attnP[wv][2 * l]     = acc.x;
        attnP[wv][2 * l + 1] = acc.y;
    }
    __syncthreads();

    // Score partial + GRU gates.
    if (t < HID) {
        float ah = 0.f;
        #pragma unroll
        for (int g = 0; g < 8; ++g) ah += attnP[g][t];
        red[t] = xv[t] * W_score[t] + ah * W_score[HID + t];
        const float r = 1.f / (1.f + expf(-(giW[t] + ghW[t])));
        const float z = 1.f / (1.f + expf(-(giW[HID + t] + ghW[HID + t])));
        const float n = tanhf(giW[2 * HID + t] + r * ghW[2 * HID + t]);
        out[1 + t] = (1.f - z) * n + z * h0[t];
    }
    __syncthreads();

    if (t < 64) {
        float sv = red[t] + red[64 + t];
        #pragma unroll
        for (int o = 32; o; o >>= 1) sv += __shfl_xor(sv, o);
        if (t == 0) out[0] = sv + b_score[0];
    }
}

extern "C" void kernel_launch(void* const* d_in, const int* in_sizes, int n_in,
                              void* d_out, int out_size, void* d_ws, size_t ws_size,
                              hipStream_t stream) {
    const float* v       = (const float*)d_in[0];
    const float* s_in    = (const float*)d_in[1];
    const float* t_in    = (const float*)d_in[2];
    const float* vs      = (const float*)d_in[3];
    const float* hs      = (const float*)d_in[4];
    const float* ts      = (const float*)d_in[5];
    const float* W_ih    = (const float*)d_in[6];
    const float* b_ih    = (const float*)d_in[7];
    const float* W_hh    = (const float*)d_in[8];
    const float* b_hh    = (const float*)d_in[9];
    const float* W_score = (const float*)d_in[10];
    const float* b_score = (const float*)d_in[11];
    float* out = (float*)d_out;

    unsigned* ws   = (unsigned*)d_ws;
    unsigned* ctrl = ws + WS_CTRL;
    unsigned* tot  = ws + WS_TOT;
    float*    alpha = (float*)(ws + WS_ALPHA);
    float*    poolV = (float*)(ws + WS_POOLV);
    unsigned* poolI = ws + WS_POOLI;
    float*    giW   = (float*)(ws + WS_GI);
    float*    ghW   = (float*)(ws + WS_GH);

    alpha_kernel<<<3125, 256, 0, stream>>>(vs, v, alpha, ws);
    hist_kernel<<<NHISTBLK, 256, 0, stream>>>(alpha, tot, ctrl);
    mid_kernel<<<NCOLLECT + 96, 256, 0, stream>>>(alpha, ctrl, poolV, poolI,
                                                  v, s_in, hs, W_ih, b_ih, W_hh, b_hh,
                                                  giW, ghW);
    final_kernel<<<1, 512, 0, stream>>>(v, t_in, hs, ts, W_score, b_score,
                                        ctrl, poolV, poolI, giW, ghW, out);
}

// Round 9
// 66.758 us; speedup vs baseline: 10.2108x; 1.0090x over previous
//
#include <hip/hip_runtime.h>
#include <math.h>

#define N_HIST 200000
#define TOPIC 128
#define HID 128
#define KSEL 50
#define NBINS 1024           // 10-bit order-key bins (sign+8exp+1mant)
#define NHISTBLK 64
#define NCOLLECT 128
#define NGRUBLK 96
#define NMID (NCOLLECT + NGRUBLK)
#define NPOOL 32
#define POOL_CAP 512
#define NEG_INF (-3.402823466e38f)
// log(float32(1.0 - 1e-7)) = log(0.99999988079071045)
#define LOG_DECAY (-1.1920930e-07f)

// ws layout (4-byte words): ctrl+tot+hist2 zeroed by alpha_kernel's first blocks.
enum { WS_CTRL  = 0,                       // [0]=hist ticket [1]=mid ticket [2]=B [3]=cHi [8..39] pool counts
       WS_TOT   = 64,                      // 1024
       WS_HIST2 = WS_TOT + NBINS,          // 2048 sub-bin histogram
       WS_ZEND  = WS_HIST2 + 2048,         // 3136 = zero region end
       WS_ALPHA = WS_ZEND,                 // 200000
       WS_POOLV = WS_ALPHA + N_HIST,       // 16384
       WS_POOLI = WS_POOLV + NPOOL * POOL_CAP,  // 16384
       WS_GI    = WS_POOLI + NPOOL * POOL_CAP,  // 384
       WS_GH    = WS_GI + 3 * HID };            // 384

__device__ __forceinline__ unsigned keyOf(float f) {
    unsigned u = __float_as_uint(f);
    return (u & 0x80000000u) ? ~u : (u | 0x80000000u);
}

// Kernel 1: alpha[i] = dot(vs[i], v); first blocks also zero ctrl+tot+hist2.
__global__ __launch_bounds__(256) void alpha_kernel(
        const float* __restrict__ vs, const float* __restrict__ v,
        float* __restrict__ alpha, unsigned* __restrict__ wsbase) {
    const int zi = blockIdx.x * 256 + threadIdx.x;
    if (zi < WS_ZEND) wsbase[zi] = 0;
    const int lane = threadIdx.x & 63;
    const int wave = (blockIdx.x * blockDim.x + threadIdx.x) >> 6;
    const int half = lane >> 5;
    const int c = lane & 31;
    const int base = wave * 16 + half * 8;
    const float4 vv = ((const float4*)v)[c];
    float4 a[8];
    #pragma unroll
    for (int r = 0; r < 8; ++r)
        a[r] = ((const float4*)vs)[(size_t)(base + r) * 32 + c];
    float s[8];
    #pragma unroll
    for (int r = 0; r < 8; ++r)
        s[r] = a[r].x * vv.x + a[r].y * vv.y + a[r].z * vv.z + a[r].w * vv.w;
    #pragma unroll
    for (int off = 16; off; off >>= 1) {
        #pragma unroll
        for (int r = 0; r < 8; ++r) s[r] += __shfl_xor(s[r], off);
    }
    if (c == 0) {
        float4* dst = (float4*)(alpha + base);
        dst[0] = make_float4(s[0], s[1], s[2], s[3]);
        dst[1] = make_float4(s[4], s[5], s[6], s[7]);
    }
}

// Kernel 2: 10-bit histogram (float4 reads, packed 2x16-bit LDS bins, global
// merge of nonzero bins) + threshold scan in the LAST block, wave-parallel.
__global__ __launch_bounds__(256) void hist_kernel(
        const float* __restrict__ alpha, unsigned* __restrict__ tot,
        unsigned* __restrict__ ctrl) {
    __shared__ unsigned h[NBINS / 2];
    __shared__ unsigned lt[NBINS];
    __shared__ int sLast;
    const int t = threadIdx.x;
    #pragma unroll
    for (int i = t; i < NBINS / 2; i += 256) h[i] = 0;
    __syncthreads();
    const float4* a4 = (const float4*)alpha;
    for (int i4 = blockIdx.x * 256 + t; i4 < N_HIST / 4; i4 += NHISTBLK * 256) {
        float4 av = a4[i4];
        #pragma unroll
        for (int r = 0; r < 4; ++r) {
            unsigned b = keyOf((&av.x)[r]) >> 22;
            atomicAdd(&h[b >> 1], (b & 1u) ? 65536u : 1u);
        }
    }
    __syncthreads();
    #pragma unroll
    for (int wd = t; wd < NBINS / 2; wd += 256) {
        unsigned pk = h[wd];
        unsigned lo = pk & 0xFFFFu, hi = pk >> 16;
        if (lo) atomicAdd(&tot[2 * wd], lo);
        if (hi) atomicAdd(&tot[2 * wd + 1], hi);
    }
    __syncthreads();
    if (t == 0) {
        __threadfence();
        sLast = (atomicAdd(&ctrl[0], 1u) == NHISTBLK - 1) ? 1 : 0;
    }
    __syncthreads();
    if (sLast) {
        __threadfence();
        #pragma unroll
        for (int i = t; i < NBINS; i += 256) lt[i] = tot[i];
        __syncthreads();
        if (t < 64) {
            const int l = t;
            const int g = 63 - l;                 // lane l covers group g, descending
            unsigned s = 0;
            #pragma unroll
            for (int j = 0; j < 16; ++j) s += lt[g * 16 + j];
            unsigned pre = s;                     // inclusive prefix over descending groups
            #pragma unroll
            for (int d = 1; d <= 32; d <<= 1) {
                unsigned y = __shfl_up(pre, d);
                if (l >= d) pre += y;
            }
            unsigned long long bal = __ballot(pre >= KSEL);
            const int lstar = __ffsll(bal) - 1;
            const unsigned cumAbove = __shfl(pre - s, lstar);
            const int gstar = 63 - lstar;
            unsigned h2 = (l < 16) ? lt[gstar * 16 + (15 - l)] : 0u;
            unsigned pre2 = h2;
            #pragma unroll
            for (int d = 1; d <= 8; d <<= 1) {
                unsigned y = __shfl_up(pre2, d);
                if (l >= d) pre2 += y;
            }
            unsigned long long bal2 = __ballot((l < 16) && (cumAbove + pre2 >= KSEL));
            const int l2 = __ffsll(bal2) - 1;
            if (l == 0) ctrl[2] = (unsigned)(gstar * 16 + (15 - l2));
        }
    }
}

// Kernel 3: blocks 0..127 collect candidates (key10 >= B) into pools AND build
// the global sub-bin histogram (bits [21:11]) of ==B candidates + cHi counter;
// blocks 128..223 do GRU matvecs. LAST arriving block runs the finale:
// B2 scan -> top-50 set -> decay+softmax+attn+score+GRU gates.
__global__ __launch_bounds__(256) void mid_kernel(
        const float* __restrict__ alpha, unsigned* __restrict__ ctrl,
        unsigned* __restrict__ hist2g,
        float* __restrict__ poolV, unsigned* __restrict__ poolI,
        const float* __restrict__ v, const float* __restrict__ s_in,
        const float* __restrict__ t_in,
        const float* __restrict__ hs, const float* __restrict__ ts,
        const float* __restrict__ W_ih, const float* __restrict__ b_ih,
        const float* __restrict__ W_hh, const float* __restrict__ b_hh,
        const float* __restrict__ W_score, const float* __restrict__ b_score,
        float* __restrict__ giW, float* __restrict__ ghW,
        float* __restrict__ out) {
    __shared__ unsigned pcnt[NPOOL];
    __shared__ unsigned selCnt, eqCnt, sB2;
    __shared__ int sLast;
    __shared__ float selV[64];
    __shared__ unsigned selI[64];
    __shared__ float eqV[256];
    __shared__ unsigned eqI[256];
    __shared__ float w[64];
    __shared__ float xv[TOPIC];
    __shared__ float h0[HID];
    __shared__ float attnP[4][130];
    __shared__ float red[HID];

    const int t = threadIdx.x;
    const int wv = t >> 6, l = t & 63;

    if (blockIdx.x < NCOLLECT) {
        const unsigned B = ctrl[2];
        const int pool = blockIdx.x & (NPOOL - 1);
        const float4* a4 = (const float4*)alpha;
        for (int i4 = blockIdx.x * 256 + t; i4 < N_HIST / 4; i4 += NCOLLECT * 256) {
            float4 av = a4[i4];
            #pragma unroll
            for (int r = 0; r < 4; ++r) {
                float a = (&av.x)[r];
                unsigned k = keyOf(a);
                unsigned top = k >> 22;
                bool cand = top >= B;
                unsigned long long m = __ballot(cand);
                if (m) {
                    int leader = __ffsll(m) - 1;
                    unsigned base = 0;
                    if (l == leader) base = atomicAdd(&ctrl[8 + pool], (unsigned)__popcll(m));
                    base = __shfl(base, leader);
                    if (cand) {
                        unsigned pos = base + (unsigned)__popcll(m & ((1ull << l) - 1ull));
                        if (pos < POOL_CAP) {
                            poolV[pool * POOL_CAP + pos] = a;
                            poolI[pool * POOL_CAP + pos] = (unsigned)(4 * i4 + r);
                        }
                        if (top > B) atomicAdd(&ctrl[3], 1u);
                        else atomicAdd(&hist2g[(k >> 11) & 2047], 1u);
                    }
                }
            }
        }
    } else {
        // GRU matvec: one wave per output row o.
        const int o = ((int)blockIdx.x - NCOLLECT) * 4 + wv;
        const float* wi = W_ih + (size_t)o * (TOPIC + 1);
        float pi = wi[l] * v[l] + wi[64 + l] * v[64 + l];
        if (l == 0) pi += wi[TOPIC] * s_in[0];
        const float2 wh = ((const float2*)(W_hh + (size_t)o * HID))[l];
        const float2 hh = ((const float2*)(hs + (size_t)(N_HIST - 1) * HID))[l];
        float ph = wh.x * hh.x + wh.y * hh.y;
        #pragma unroll
        for (int off = 32; off; off >>= 1) {
            pi += __shfl_xor(pi, off);
            ph += __shfl_xor(ph, off);
        }
        if (l == 0) {
            giW[o] = pi + b_ih[o];
            ghW[o] = ph + b_hh[o];
        }
    }

    // ---- ticket: last arriving block runs the finale on a warm CU ----
    __syncthreads();
    if (t == 0) {
        __threadfence();
        sLast = (atomicAdd(&ctrl[1], 1u) == NMID - 1) ? 1 : 0;
    }
    __syncthreads();
    if (!sLast) return;
    __threadfence();

    const unsigned B = ctrl[2];
    const unsigned cHi = ctrl[3];

    // stage small vectors + pool counts
    if (t < NPOOL) pcnt[t] = min(ctrl[8 + t], (unsigned)POOL_CAP);
    if (t == 0) { selCnt = 0; eqCnt = 0; }
    if (t < 128) xv[t] = v[t];
    else h0[t - 128] = hs[(size_t)(N_HIST - 1) * HID + (t - 128)];
    __syncthreads();

    // B2 scan over hist2g (2048 bins, descending, two-level 64x32), wave 0.
    if (wv == 0) {
        const int g = 63 - l;
        const uint4* h4 = (const uint4*)(hist2g + g * 32);
        unsigned s = 0;
        #pragma unroll
        for (int j = 0; j < 8; ++j) { uint4 q = h4[j]; s += q.x + q.y + q.z + q.w; }
        unsigned pre = s;
        #pragma unroll
        for (int d = 1; d <= 32; d <<= 1) {
            unsigned y = __shfl_up(pre, d);
            if (l >= d) pre += y;
        }
        unsigned long long bal = __ballot(cHi + pre >= KSEL);
        const int lstar = __ffsll(bal) - 1;
        const unsigned cumAbove = cHi + __shfl(pre - s, lstar);
        const int gstar = 63 - lstar;
        unsigned h2 = (l < 32) ? hist2g[gstar * 32 + (31 - l)] : 0u;
        unsigned pre2 = h2;
        #pragma unroll
        for (int d = 1; d <= 16; d <<= 1) {
            unsigned y = __shfl_up(pre2, d);
            if (l >= d) pre2 += y;
        }
        unsigned long long bal2 = __ballot((l < 32) && (cumAbove + pre2 >= KSEL));
        const int l2 = __ffsll(bal2) - 1;
        if (l == 0) sB2 = (unsigned)(gstar * 32 + (31 - l2));
    }
    __syncthreads();
    const unsigned B2 = sB2;

    // Pass B: filter pools -> strictly-above set (unordered) + tie pool.
    for (int j = t; j < NPOOL * POOL_CAP; j += 256) {
        const int p = j >> 9;               // POOL_CAP = 512
        const int idx = j & (POOL_CAP - 1);
        if (idx < (int)pcnt[p]) {
            float a = poolV[j];
            unsigned k = keyOf(a);
            unsigned top = k >> 22, sub = (k >> 11) & 2047;
            bool hi = (top > B) || (top == B && sub > B2);
            bool eq = (top == B) && (sub == B2);
            if (hi) {
                unsigned pos = atomicAdd(&selCnt, 1u);
                if (pos < 64u) { selV[pos] = a; selI[pos] = poolI[j]; }
            } else if (eq) {
                unsigned pos = atomicAdd(&eqCnt, 1u);
                if (pos < 256u) { eqV[pos] = a; eqI[pos] = poolI[j]; }
            }
        }
    }
    __syncthreads();

    const int Scnt = min((int)selCnt, 64);      // guaranteed < KSEL by B construction
    const int eqN = min((int)eqCnt, 256);
    int need = KSEL - Scnt;
    if (need < 0) need = 0;
    if (need > eqN) need = eqN;
    const int S = Scnt + need;

    // Rank tie pool exactly (value desc, index asc); eqN is tiny.
    if (wv == 0 && need > 0) {
        for (int c = l; c < eqN; c += 64) {
            const float mv = eqV[c];
            const unsigned mi = eqI[c];
            int r = 0;
            for (int j = 0; j < eqN; ++j) {
                const float vj = eqV[j];
                const unsigned ij = eqI[j];
                r += (int)((vj > mv) | ((vj == mv) & (ij < mi)));
            }
            if (r < need) { selV[Scnt + r] = mv; selI[Scnt + r] = mi; }
        }
    }
    __syncthreads();

    // Decay + softmax on wave 0 (order-invariant downstream).
    if (wv == 0) {
        const float tt = t_in[0];
        float dv = NEG_INF;
        if (l < S) dv = selV[l] * expf((tt - ts[selI[l]]) * LOG_DECAY);
        float m = dv;
        #pragma unroll
        for (int o = 32; o; o >>= 1) m = fmaxf(m, __shfl_xor(m, o));
        float e = (l < S) ? expf(dv - m) : 0.f;
        float sum = e;
        #pragma unroll
        for (int o = 32; o; o >>= 1) sum += __shfl_xor(sum, o);
        if (l < S) w[l] = e / sum;
    }
    __syncthreads();

    // Attn partials; 4 waves x 13 fixed trips -> independent gathers.
    {
        float2 acc = make_float2(0.f, 0.f);
        #pragma unroll
        for (int j = 0; j < 13; ++j) {
            const int k = wv + 4 * j;
            const bool ok = (k < S);
            const float wk = ok ? w[k] : 0.f;
            const unsigned ridx = ok ? selI[k] : 0u;
            const float2 hv = ((const float2*)(hs + (size_t)ridx * HID))[l];
            acc.x += wk * hv.x; acc.y += wk * hv.y;
        }
        attnP[wv][2 * l]     = acc.x;
        attnP[wv][2 * l + 1] = acc.y;
    }
    __syncthreads();

    // Score partial + GRU gates.
    if (t < HID) {
        float ah = attnP[0][t] + attnP[1][t] + attnP[2][t] + attnP[3][t];
        red[t] = xv[t] * W_score[t] + ah * W_score[HID + t];
        const float r = 1.f / (1.f + expf(-(giW[t] + ghW[t])));
        const float z = 1.f / (1.f + expf(-(giW[HID + t] + ghW[HID + t])));
        const float n = tanhf(giW[2 * HID + t] + r * ghW[2 * HID + t]);
        out[1 + t] = (1.f - z) * n + z * h0[t];
    }
    __syncthreads();

    if (t < 64) {
        float sv = red[t] + red[64 + t];
        #pragma unroll
        for (int o = 32; o; o >>= 1) sv += __shfl_xor(sv, o);
        if (t == 0) out[0] = sv + b_score[0];
    }
}

extern "C" void kernel_launch(void* const* d_in, const int* in_sizes, int n_in,
                              void* d_out, int out_size, void* d_ws, size_t ws_size,
                              hipStream_t stream) {
    const float* v       = (const float*)d_in[0];
    const float* s_in    = (const float*)d_in[1];
    const float* t_in    = (const float*)d_in[2];
    const float* vs      = (const float*)d_in[3];
    const float* hs      = (const float*)d_in[4];
    const float* ts      = (const float*)d_in[5];
    const float* W_ih    = (const float*)d_in[6];
    const float* b_ih    = (const float*)d_in[7];
    const float* W_hh    = (const float*)d_in[8];
    const float* b_hh    = (const float*)d_in[9];
    const float* W_score = (const float*)d_in[10];
    const float* b_score = (const float*)d_in[11];
    float* out = (float*)d_out;

    unsigned* ws     = (unsigned*)d_ws;
    unsigned* ctrl   = ws + WS_CTRL;
    unsigned* tot    = ws + WS_TOT;
    unsigned* hist2g = ws + WS_HIST2;
    float*    alpha  = (float*)(ws + WS_ALPHA);
    float*    poolV  = (float*)(ws + WS_POOLV);
    unsigned* poolI  = ws + WS_POOLI;
    float*    giW    = (float*)(ws + WS_GI);
    float*    ghW    = (float*)(ws + WS_GH);

    alpha_kernel<<<3125, 256, 0, stream>>>(vs, v, alpha, ws);
    hist_kernel<<<NHISTBLK, 256, 0, stream>>>(alpha, tot, ctrl);
    mid_kernel<<<NMID, 256, 0, stream>>>(alpha, ctrl, hist2g, poolV, poolI,
                                         v, s_in, t_in, hs, ts,
                                         W_ih, b_ih, W_hh, b_hh, W_score, b_score,
                                         giW, ghW, out);
}

// Round 10
// 42.520 us; speedup vs baseline: 16.0311x; 1.5700x over previous
//
#include <hip/hip_runtime.h>
#include <math.h>

#define N_HIST 200000
#define TOPIC 128
#define HID 128
#define KSEL 50
#define NBINS 4096           // 12-bit order-key bins (sign+8exp+3mant)
#define NHISTBLK 64
#define NCOLLECT 128
#define NGRUBLK 96
#define NMID (NCOLLECT + NGRUBLK)
#define NPOOL 32
#define POOL_CAP 256
#define NEG_INF (-3.402823466e38f)
// log(float32(1.0 - 1e-7)) = log(0.99999988079071045)
#define LOG_DECAY (-1.1920930e-07f)

// ws layout (4-byte words): ctrl+tot+hist2 zeroed by alpha_kernel's first blocks.
enum { WS_CTRL  = 0,                       // [0]=hist ticket [1]=mid ticket [2]=B [3]=cHi [8..39] pool counts
       WS_TOT   = 64,                      // 4096
       WS_HIST2 = WS_TOT + NBINS,          // 2048 sub-bin histogram (bits 19:9 of ==B)
       WS_ZEND  = WS_HIST2 + 2048,         // 6208 = zero region end
       WS_ALPHA = WS_ZEND,                 // 200000
       WS_POOLV = WS_ALPHA + N_HIST,       // 8192
       WS_POOLI = WS_POOLV + NPOOL * POOL_CAP,  // 8192
       WS_GI    = WS_POOLI + NPOOL * POOL_CAP,  // 384
       WS_GH    = WS_GI + 3 * HID };            // 384

__device__ __forceinline__ unsigned keyOf(float f) {
    unsigned u = __float_as_uint(f);
    return (u & 0x80000000u) ? ~u : (u | 0x80000000u);
}

// Kernel 1: alpha[i] = dot(vs[i], v); first 25 blocks also zero ctrl+tot+hist2.
__global__ __launch_bounds__(256) void alpha_kernel(
        const float* __restrict__ vs, const float* __restrict__ v,
        float* __restrict__ alpha, unsigned* __restrict__ wsbase) {
    const int zi = blockIdx.x * 256 + threadIdx.x;
    if (zi < WS_ZEND) wsbase[zi] = 0;
    const int lane = threadIdx.x & 63;
    const int wave = (blockIdx.x * blockDim.x + threadIdx.x) >> 6;
    const int half = lane >> 5;
    const int c = lane & 31;
    const int base = wave * 16 + half * 8;
    const float4 vv = ((const float4*)v)[c];
    float4 a[8];
    #pragma unroll
    for (int r = 0; r < 8; ++r)
        a[r] = ((const float4*)vs)[(size_t)(base + r) * 32 + c];
    float s[8];
    #pragma unroll
    for (int r = 0; r < 8; ++r)
        s[r] = a[r].x * vv.x + a[r].y * vv.y + a[r].z * vv.z + a[r].w * vv.w;
    #pragma unroll
    for (int off = 16; off; off >>= 1) {
        #pragma unroll
        for (int r = 0; r < 8; ++r) s[r] += __shfl_xor(s[r], off);
    }
    if (c == 0) {
        float4* dst = (float4*)(alpha + base);
        dst[0] = make_float4(s[0], s[1], s[2], s[3]);
        dst[1] = make_float4(s[4], s[5], s[6], s[7]);
    }
}

// Kernel 2: 12-bit histogram (float4 reads, packed 2x16-bit LDS bins, global
// merge of nonzero bins) + threshold scan in the LAST block, wave-parallel
// two-level 64x64 descending scan.
__global__ __launch_bounds__(256) void hist_kernel(
        const float* __restrict__ alpha, unsigned* __restrict__ tot,
        unsigned* __restrict__ ctrl) {
    __shared__ unsigned h[NBINS / 2];
    __shared__ unsigned lt[NBINS];
    __shared__ int sLast;
    const int t = threadIdx.x;
    #pragma unroll
    for (int i = t; i < NBINS / 2; i += 256) h[i] = 0;
    __syncthreads();
    const float4* a4 = (const float4*)alpha;
    for (int i4 = blockIdx.x * 256 + t; i4 < N_HIST / 4; i4 += NHISTBLK * 256) {
        float4 av = a4[i4];
        #pragma unroll
        for (int r = 0; r < 4; ++r) {
            unsigned b = keyOf((&av.x)[r]) >> 20;
            atomicAdd(&h[b >> 1], (b & 1u) ? 65536u : 1u);
        }
    }
    __syncthreads();
    #pragma unroll
    for (int wd = t; wd < NBINS / 2; wd += 256) {
        unsigned pk = h[wd];
        unsigned lo = pk & 0xFFFFu, hi = pk >> 16;
        if (lo) atomicAdd(&tot[2 * wd], lo);
        if (hi) atomicAdd(&tot[2 * wd + 1], hi);
    }
    __syncthreads();
    if (t == 0) {
        __threadfence();
        sLast = (atomicAdd(&ctrl[0], 1u) == NHISTBLK - 1) ? 1 : 0;
    }
    __syncthreads();
    if (sLast) {
        __threadfence();
        #pragma unroll
        for (int i = t; i < NBINS; i += 256) lt[i] = tot[i];
        __syncthreads();
        if (t < 64) {
            const int l = t;
            const int g = 63 - l;                 // lane l covers group g, descending
            unsigned s = 0;
            #pragma unroll
            for (int j = 0; j < 64; ++j) s += lt[g * 64 + j];
            unsigned pre = s;                     // inclusive prefix over descending groups
            #pragma unroll
            for (int d = 1; d <= 32; d <<= 1) {
                unsigned y = __shfl_up(pre, d);
                if (l >= d) pre += y;
            }
            unsigned long long bal = __ballot(pre >= KSEL);
            const int lstar = __ffsll(bal) - 1;
            const unsigned cumAbove = __shfl(pre - s, lstar);
            const int gstar = 63 - lstar;
            unsigned h2 = lt[gstar * 64 + (63 - l)];
            unsigned pre2 = h2;
            #pragma unroll
            for (int d = 1; d <= 32; d <<= 1) {
                unsigned y = __shfl_up(pre2, d);
                if (l >= d) pre2 += y;
            }
            unsigned long long bal2 = __ballot(cumAbove + pre2 >= KSEL);
            const int l2 = __ffsll(bal2) - 1;
            if (l == 0) ctrl[2] = (unsigned)(gstar * 64 + (63 - l2));
        }
    }
}

// Kernel 3: blocks 0..127 collect candidates (key12 >= B) into pools AND build
// the global sub-bin histogram (bits 19:9) of ==B candidates + cHi counter;
// blocks 128..223 do GRU matvecs. LAST arriving block runs the finale.
__global__ __launch_bounds__(256) void mid_kernel(
        const float* __restrict__ alpha, unsigned* __restrict__ ctrl,
        unsigned* __restrict__ hist2g,
        float* __restrict__ poolV, unsigned* __restrict__ poolI,
        const float* __restrict__ v, const float* __restrict__ s_in,
        const float* __restrict__ t_in,
        const float* __restrict__ hs, const float* __restrict__ ts,
        const float* __restrict__ W_ih, const float* __restrict__ b_ih,
        const float* __restrict__ W_hh, const float* __restrict__ b_hh,
        const float* __restrict__ W_score, const float* __restrict__ b_score,
        float* __restrict__ giW, float* __restrict__ ghW,
        float* __restrict__ out) {
    __shared__ unsigned pcnt[NPOOL];
    __shared__ unsigned selCnt, eqCnt, sB2;
    __shared__ int sLast;
    __shared__ float selV[64];
    __shared__ unsigned selI[64];
    __shared__ float eqV[256];
    __shared__ unsigned eqI[256];
    __shared__ float w[64];
    __shared__ float xv[TOPIC];
    __shared__ float h0[HID];
    __shared__ float attnP[4][130];
    __shared__ float red[HID];

    const int t = threadIdx.x;
    const int wv = t >> 6, l = t & 63;

    if (blockIdx.x < NCOLLECT) {
        const unsigned B = ctrl[2];
        const int pool = blockIdx.x & (NPOOL - 1);
        const float4* a4 = (const float4*)alpha;
        for (int i4 = blockIdx.x * 256 + t; i4 < N_HIST / 4; i4 += NCOLLECT * 256) {
            float4 av = a4[i4];
            #pragma unroll
            for (int r = 0; r < 4; ++r) {
                float a = (&av.x)[r];
                unsigned k = keyOf(a);
                unsigned top = k >> 20;
                bool cand = top >= B;
                unsigned long long m = __ballot(cand);
                if (m) {
                    int leader = __ffsll(m) - 1;
                    unsigned base = 0;
                    if (l == leader) base = atomicAdd(&ctrl[8 + pool], (unsigned)__popcll(m));
                    base = __shfl(base, leader);
                    if (cand) {
                        unsigned pos = base + (unsigned)__popcll(m & ((1ull << l) - 1ull));
                        if (pos < POOL_CAP) {
                            poolV[pool * POOL_CAP + pos] = a;
                            poolI[pool * POOL_CAP + pos] = (unsigned)(4 * i4 + r);
                        }
                        if (top > B) atomicAdd(&ctrl[3], 1u);
                        else atomicAdd(&hist2g[(k >> 9) & 2047], 1u);
                    }
                }
            }
        }
    } else {
        // GRU matvec: one wave per output row o.
        const int o = ((int)blockIdx.x - NCOLLECT) * 4 + wv;
        const float* wi = W_ih + (size_t)o * (TOPIC + 1);
        float pi = wi[l] * v[l] + wi[64 + l] * v[64 + l];
        if (l == 0) pi += wi[TOPIC] * s_in[0];
        const float2 wh = ((const float2*)(W_hh + (size_t)o * HID))[l];
        const float2 hh = ((const float2*)(hs + (size_t)(N_HIST - 1) * HID))[l];
        float ph = wh.x * hh.x + wh.y * hh.y;
        #pragma unroll
        for (int off = 32; off; off >>= 1) {
            pi += __shfl_xor(pi, off);
            ph += __shfl_xor(ph, off);
        }
        if (l == 0) {
            giW[o] = pi + b_ih[o];
            ghW[o] = ph + b_hh[o];
        }
    }

    // ---- ticket: last arriving block runs the finale on a warm CU ----
    __syncthreads();
    if (t == 0) {
        __threadfence();
        sLast = (atomicAdd(&ctrl[1], 1u) == NMID - 1) ? 1 : 0;
    }
    __syncthreads();
    if (!sLast) return;
    __threadfence();

    const unsigned B = ctrl[2];
    const unsigned cHi = ctrl[3];

    // Phase F0: wave0 = B2 scan over hist2g (2048 bins, 64x32 descending);
    //           waves1-3 = stage pcnt + h0; zero counters.
    if (wv == 0) {
        const int g = 63 - l;
        const uint4* h4 = (const uint4*)(hist2g + g * 32);
        unsigned s = 0;
        #pragma unroll
        for (int j = 0; j < 8; ++j) { uint4 q = h4[j]; s += q.x + q.y + q.z + q.w; }
        unsigned pre = s;
        #pragma unroll
        for (int d = 1; d <= 32; d <<= 1) {
            unsigned y = __shfl_up(pre, d);
            if (l >= d) pre += y;
        }
        unsigned long long bal = __ballot(cHi + pre >= KSEL);
        const int lstar = __ffsll(bal) - 1;
        const unsigned cumAbove = cHi + __shfl(pre - s, lstar);
        const int gstar = 63 - lstar;
        unsigned h2 = (l < 32) ? hist2g[gstar * 32 + (31 - l)] : 0u;
        unsigned pre2 = h2;
        #pragma unroll
        for (int d = 1; d <= 16; d <<= 1) {
            unsigned y = __shfl_up(pre2, d);
            if (l >= d) pre2 += y;
        }
        unsigned long long bal2 = __ballot((l < 32) && (cumAbove + pre2 >= KSEL));
        const int l2 = __ffsll(bal2) - 1;
        if (l == 0) sB2 = (unsigned)(gstar * 32 + (31 - l2));
    } else {
        if (t >= 64 && t < 96) pcnt[t - 64] = min(ctrl[8 + (t - 64)], (unsigned)POOL_CAP);
        if (t == 96) { selCnt = 0; eqCnt = 0; }
        if (t >= 128 && t < 256) h0[t - 128] = hs[(size_t)(N_HIST - 1) * HID + (t - 128)];
    }
    __syncthreads();
    const unsigned B2 = sB2;

    // Phase F1: filter candidates (8 threads/pool, iterate actual counts only).
    {
        const int p = t >> 3, i0 = t & 7;
        const int cnt = (int)pcnt[p];
        for (int i = i0; i < cnt; i += 8) {
            float a = poolV[p * POOL_CAP + i];
            unsigned k = keyOf(a);
            unsigned top = k >> 20, sub = (k >> 9) & 2047;
            bool hi = (top > B) || (top == B && sub > B2);
            bool eq = (top == B) && (sub == B2);
            if (hi) {
                unsigned pos = atomicAdd(&selCnt, 1u);
                if (pos < 64u) { selV[pos] = a; selI[pos] = poolI[p * POOL_CAP + i]; }
            } else if (eq) {
                unsigned pos = atomicAdd(&eqCnt, 1u);
                if (pos < 256u) { eqV[pos] = a; eqI[pos] = poolI[p * POOL_CAP + i]; }
            }
        }
    }
    __syncthreads();

    const int Scnt = min((int)selCnt, 64);      // < KSEL by B2 construction
    const int eqN = min((int)eqCnt, 256);
    int need = KSEL - Scnt;
    if (need < 0) need = 0;
    if (need > eqN) need = eqN;
    const int S = Scnt + need;

    // Phase F2: wave0 = exact rank of tie pool (23-bit-equal, tiny);
    //           others stage xv.
    if (wv == 0) {
        if (need > 0) {
            for (int c = l; c < eqN; c += 64) {
                const float mv = eqV[c];
                const unsigned mi = eqI[c];
                int r = 0;
                for (int j = 0; j < eqN; ++j) {
                    const float vj = eqV[j];
                    const unsigned ij = eqI[j];
                    r += (int)((vj > mv) | ((vj == mv) & (ij < mi)));
                }
                if (r < need) { selV[Scnt + r] = mv; selI[Scnt + r] = mi; }
            }
        }
    } else if (t >= 128 && t < 256) {
        xv[t - 128] = v[t - 128];
    }
    __syncthreads();

    // Phase F3: all waves issue their attn hs gathers (overlaps wave0 softmax).
    unsigned ridx[13];
    float2 hv[13];
    #pragma unroll
    for (int j = 0; j < 13; ++j) {
        const int k = wv + 4 * j;
        ridx[j] = (k < S) ? selI[k] : 0u;
    }
    #pragma unroll
    for (int j = 0; j < 13; ++j)
        hv[j] = ((const float2*)(hs + (size_t)ridx[j] * HID))[l];

    if (wv == 0) {
        const float tt = t_in[0];
        float dv = NEG_INF;
        if (l < S) dv = selV[l] * expf((tt - ts[selI[l]]) * LOG_DECAY);
        float m = dv;
        #pragma unroll
        for (int o = 32; o; o >>= 1) m = fmaxf(m, __shfl_xor(m, o));
        float e = (l < S) ? expf(dv - m) : 0.f;
        float sum = e;
        #pragma unroll
        for (int o = 32; o; o >>= 1) sum += __shfl_xor(sum, o);
        if (l < S) w[l] = e / sum;
    }
    __syncthreads();

    // Phase F4: weighted accumulate + attnP write.
    {
        float2 acc = make_float2(0.f, 0.f);
        #pragma unroll
        for (int j = 0; j < 13; ++j) {
            const int k = wv + 4 * j;
            const float wk = (k < S) ? w[k] : 0.f;
            acc.x += wk * hv[j].x; acc.y += wk * hv[j].y;
        }
        attnP[wv][2 * l]     = acc.x;
        attnP[wv][2 * l + 1] = acc.y;
    }
    __syncthreads();

    // Phase F5: score partial + GRU gates.
    if (t < HID) {
        float ah = attnP[0][t] + attnP[1][t] + attnP[2][t] + attnP[3][t];
        red[t] = xv[t] * W_score[t] + ah * W_score[HID + t];
        const float r = 1.f / (1.f + expf(-(giW[t] + ghW[t])));
        const float z = 1.f / (1.f + expf(-(giW[HID + t] + ghW[HID + t])));
        const float n = tanhf(giW[2 * HID + t] + r * ghW[2 * HID + t]);
        out[1 + t] = (1.f - z) * n + z * h0[t];
    }
    __syncthreads();

    if (t < 64) {
        float sv = red[t] + red[64 + t];
        #pragma unroll
        for (int o = 32; o; o >>= 1) sv += __shfl_xor(sv, o);
        if (t == 0) out[0] = sv + b_score[0];
    }
}

extern "C" void kernel_launch(void* const* d_in, const int* in_sizes, int n_in,
                              void* d_out, int out_size, void* d_ws, size_t ws_size,
                              hipStream_t stream) {
    const float* v       = (const float*)d_in[0];
    const float* s_in    = (const float*)d_in[1];
    const float* t_in    = (const float*)d_in[2];
    const float* vs      = (const float*)d_in[3];
    const float* hs      = (const float*)d_in[4];
    const float* ts      = (const float*)d_in[5];
    const float* W_ih    = (const float*)d_in[6];
    const float* b_ih    = (const float*)d_in[7];
    const float* W_hh    = (const float*)d_in[8];
    const float* b_hh    = (const float*)d_in[9];
    const float* W_score = (const float*)d_in[10];
    const float* b_score = (const float*)d_in[11];
    float* out = (float*)d_out;

    unsigned* ws     = (unsigned*)d_ws;
    unsigned* ctrl   = ws + WS_CTRL;
    unsigned* tot    = ws + WS_TOT;
    unsigned* hist2g = ws + WS_HIST2;
    float*    alpha  = (float*)(ws + WS_ALPHA);
    float*    poolV  = (float*)(ws + WS_POOLV);
    unsigned* poolI  = ws + WS_POOLI;
    float*    giW    = (float*)(ws + WS_GI);
    float*    ghW    = (float*)(ws + WS_GH);

    alpha_kernel<<<3125, 256, 0, stream>>>(vs, v, alpha, ws);
    hist_kernel<<<NHISTBLK, 256, 0, stream>>>(alpha, tot, ctrl);
    mid_kernel<<<NMID, 256, 0, stream>>>(alpha, ctrl, hist2g, poolV, poolI,
                                         v, s_in, t_in, hs, ts,
                                         W_ih, b_ih, W_hh, b_hh, W_score, b_score,
                                         giW, ghW, out);
}